// Round 13
// baseline (233.120 us; speedup 1.0000x reference)
//
#include <hip/hip_runtime.h>
#include <hip/hip_bf16.h>

// GraphConv x2 via dst-sorted CSR gather (no float atomics):
//   xbf16:      x -> bf16 copy (gathered operand only; root path stays fp32)
//   gather1:    aggm = mean_e w*x_bf16[src]          (traffic-bound: halve bytes)
//   node_fused: lane=node, scalar weights, LDS act tile stride 65
//   gather2:    out = mean_e w*hr_bf16[src] + hro
// CSR build: hist(rank=atomicAdd ret, 4-edge ILP) -> scan -> atomic-free fill.
// bf16 budget: RNE rel-err 2^-9; predicted absmax ~0.02 vs 0.049 threshold.

#define NF 64

__device__ __forceinline__ unsigned short f2bf(float f) {
    __hip_bfloat16 h = __float2bfloat16(f);
    return *reinterpret_cast<unsigned short*>(&h);
}
__device__ __forceinline__ float bf2f(unsigned short u) {
    return __uint_as_float((unsigned int)u << 16);
}

// ---------------- dtype detection (int64 vs int32 edge_index) ---------------
__global__ void detect_i64(const unsigned* __restrict__ raw, int* __restrict__ flag, int E) {
    __shared__ unsigned red[256];
    unsigned v = 0;
    int lim = (E < 4096) ? E : 4096;
    for (int i = threadIdx.x; i < lim; i += 256) v |= raw[2 * i + 1];
    red[threadIdx.x] = v;
    __syncthreads();
    for (int s = 128; s > 0; s >>= 1) {
        if (threadIdx.x < s) red[threadIdx.x] |= red[threadIdx.x + s];
        __syncthreads();
    }
    if (threadIdx.x == 0) *flag = (red[0] == 0) ? 1 : 0;  // high dwords zero => int64
}

// ---------------- x -> bf16 copy ---------------------------------------------
__global__ __launch_bounds__(256) void xbf16(const float* __restrict__ x,
                                             unsigned short* __restrict__ xb,
                                             long long n4) {
    long long i = (long long)blockIdx.x * 256 + threadIdx.x;
    long long stride = (long long)gridDim.x * 256;
    for (; i < n4; i += stride) {
        float4 v = *(const float4*)(x + i * 4);
        ushort4 o;
        o.x = f2bf(v.x); o.y = f2bf(v.y); o.z = f2bf(v.z); o.w = f2bf(v.w);
        *(ushort4*)(xb + i * 4) = o;
    }
}

// ------- histogram of dst + packed (dst,rank) records; 4-edge ILP -----------
__global__ __launch_bounds__(256) void hist(const void* __restrict__ raw,
                                            const int* __restrict__ flag,
                                            int* __restrict__ deg,
                                            int2* __restrict__ dr, int E) {
    int e0 = blockIdx.x * 1024 + threadIdx.x;
    int fl = *flag;
    int d[4];
#pragma unroll
    for (int j = 0; j < 4; ++j) {
        int e = e0 + j * 256;
        d[j] = 0;
        if (e < E) {
            if (fl) d[j] = (int)__builtin_nontemporal_load(((const long long*)raw) + E + e);
            else    d[j] = __builtin_nontemporal_load(((const int*)raw) + E + e);
        }
    }
    int r[4];
#pragma unroll
    for (int j = 0; j < 4; ++j) {
        int e = e0 + j * 256;
        if (e < E) r[j] = atomicAdd(&deg[d[j]], 1);
    }
#pragma unroll
    for (int j = 0; j < 4; ++j) {
        int e = e0 + j * 256;
        if (e < E) dr[e] = make_int2(d[j], r[j]);
    }
}

// ---------------- exclusive scan (3 kernels) ---------------------------------
__global__ __launch_bounds__(1024) void scan_k1(const int* __restrict__ deg,
                                                int* __restrict__ base,
                                                int* __restrict__ bsums, int N) {
    __shared__ int tmp[1024];
    int tid = threadIdx.x;
    int i = blockIdx.x * 1024 + tid;
    int v = (i < N) ? deg[i] : 0;
    tmp[tid] = v;
    __syncthreads();
    for (int off = 1; off < 1024; off <<= 1) {
        int t = (tid >= off) ? tmp[tid - off] : 0;
        __syncthreads();
        tmp[tid] += t;
        __syncthreads();
    }
    if (i < N) base[i] = tmp[tid] - v;
    if (tid == 1023) bsums[blockIdx.x] = tmp[tid];
}

__global__ __launch_bounds__(256) void scan_k2(int* __restrict__ bsums, int nb) {
    __shared__ int tmp[256];
    int tid = threadIdx.x;
    int v = (tid < nb) ? bsums[tid] : 0;
    tmp[tid] = v;
    __syncthreads();
    for (int off = 1; off < 256; off <<= 1) {
        int t = (tid >= off) ? tmp[tid - off] : 0;
        __syncthreads();
        tmp[tid] += t;
        __syncthreads();
    }
    if (tid < nb) bsums[tid] = tmp[tid] - v;
}

__global__ __launch_bounds__(1024) void scan_k3(int* __restrict__ base,
                                                const int* __restrict__ bsums, int N) {
    int i = blockIdx.x * 1024 + threadIdx.x;
    if (i >= N) return;
    base[i] += bsums[blockIdx.x];
}

// ---------------- weight prep: transpose into [k][f] layouts -----------------
__global__ __launch_bounds__(256) void wprep(
    const float* __restrict__ Wrel1, const float* __restrict__ Wroot1,
    const float* __restrict__ Wrel2, const float* __restrict__ Wroot2,
    float* __restrict__ W1relT, float* __restrict__ W1rootT,
    float* __restrict__ W2T) {
    int t = threadIdx.x;
    for (int i = t; i < 4096; i += 256) {
        int f = i >> 6, k = i & 63;
        W1relT[k * 64 + f]  = Wrel1[f * 64 + k];
        W1rootT[k * 64 + f] = Wroot1[f * 64 + k];
        W2T[k * 64 + f] = (f < 32) ? Wrel2[f * 64 + k] : Wroot2[(f - 32) * 64 + k];
    }
}

// ---------------- fill CSR slots: atomic-free, 4-edge ILP --------------------
__global__ __launch_bounds__(256) void fill_csr(const void* __restrict__ raw,
                                                const int* __restrict__ flag,
                                                const float* __restrict__ ea,
                                                const int2* __restrict__ dr,
                                                const int* __restrict__ base,
                                                long long* __restrict__ csr, int E) {
    int e0 = blockIdx.x * 1024 + threadIdx.x;
    int fl = *flag;
    int s[4]; float w[4]; int2 drv[4];
#pragma unroll
    for (int j = 0; j < 4; ++j) {
        int e = e0 + j * 256;
        s[j] = 0; w[j] = 0.f; drv[j] = make_int2(0, 0);
        if (e < E) {
            if (fl) s[j] = (int)__builtin_nontemporal_load(((const long long*)raw) + e);
            else    s[j] = __builtin_nontemporal_load(((const int*)raw) + e);
            w[j] = __builtin_nontemporal_load(ea + e);
            drv[j] = dr[e];
        }
    }
    int slot[4];
#pragma unroll
    for (int j = 0; j < 4; ++j) {
        int e = e0 + j * 256;
        if (e < E) slot[j] = base[drv[j].x] + drv[j].y;
    }
#pragma unroll
    for (int j = 0; j < 4; ++j) {
        int e = e0 + j * 256;
        if (e < E) {
            long long packed = (unsigned int)s[j] | ((long long)__float_as_int(w[j]) << 32);
            __builtin_nontemporal_store(packed, csr + slot[j]);
        }
    }
}

// ---------------- gather1: aggm[n] = (sum_e w*xb[src])/max(deg,1) ------------
__global__ __launch_bounds__(256) void gather1(
    const unsigned short* __restrict__ xb, const int2* __restrict__ csr,
    const int* __restrict__ base, const int* __restrict__ deg,
    float* __restrict__ aggm, int N)
{
    int lane = threadIdx.x & 63;
    int wid = blockIdx.x * 4 + (threadIdx.x >> 6);
    int stride = gridDim.x * 4;
    for (int n = wid; n < N; n += stride) {
        int b = __builtin_amdgcn_readfirstlane(base[n]);
        int dg = __builtin_amdgcn_readfirstlane(deg[n]);
        float acc0 = 0.f, acc1 = 0.f, acc2 = 0.f, acc3 = 0.f;
        int i = b, e = b + dg;
        for (; i + 8 <= e; i += 8) {
            int2 r0 = csr[i], r1 = csr[i + 1], r2 = csr[i + 2], r3 = csr[i + 3];
            int2 r4 = csr[i + 4], r5 = csr[i + 5], r6 = csr[i + 6], r7 = csr[i + 7];
            float v0 = bf2f(xb[(size_t)r0.x * 64 + lane]);
            float v1 = bf2f(xb[(size_t)r1.x * 64 + lane]);
            float v2 = bf2f(xb[(size_t)r2.x * 64 + lane]);
            float v3 = bf2f(xb[(size_t)r3.x * 64 + lane]);
            float v4 = bf2f(xb[(size_t)r4.x * 64 + lane]);
            float v5 = bf2f(xb[(size_t)r5.x * 64 + lane]);
            float v6 = bf2f(xb[(size_t)r6.x * 64 + lane]);
            float v7 = bf2f(xb[(size_t)r7.x * 64 + lane]);
            acc0 = fmaf(__int_as_float(r0.y), v0, acc0);
            acc1 = fmaf(__int_as_float(r1.y), v1, acc1);
            acc2 = fmaf(__int_as_float(r2.y), v2, acc2);
            acc3 = fmaf(__int_as_float(r3.y), v3, acc3);
            acc0 = fmaf(__int_as_float(r4.y), v4, acc0);
            acc1 = fmaf(__int_as_float(r5.y), v5, acc1);
            acc2 = fmaf(__int_as_float(r6.y), v6, acc2);
            acc3 = fmaf(__int_as_float(r7.y), v7, acc3);
        }
        for (; i + 4 <= e; i += 4) {
            int2 r0 = csr[i], r1 = csr[i + 1], r2 = csr[i + 2], r3 = csr[i + 3];
            acc0 = fmaf(__int_as_float(r0.y), bf2f(xb[(size_t)r0.x * 64 + lane]), acc0);
            acc1 = fmaf(__int_as_float(r1.y), bf2f(xb[(size_t)r1.x * 64 + lane]), acc1);
            acc2 = fmaf(__int_as_float(r2.y), bf2f(xb[(size_t)r2.x * 64 + lane]), acc2);
            acc3 = fmaf(__int_as_float(r3.y), bf2f(xb[(size_t)r3.x * 64 + lane]), acc3);
        }
        for (; i < e; ++i) {
            int2 r = csr[i];
            acc0 = fmaf(__int_as_float(r.y), bf2f(xb[(size_t)r.x * 64 + lane]), acc0);
        }
        float inv = 1.0f / fmaxf((float)dg, 1.0f);
        aggm[(size_t)n * 64 + lane] = ((acc0 + acc1) + (acc2 + acc3)) * inv;
    }
}

// ---------------- node_fused v2: lane=node, scalar weights -------------------
// hr written as bf16 (gathered by gather2); hro stays fp32 (read once, coalesced).
__global__ __launch_bounds__(256) void node_fused(
    const float* __restrict__ x, const float* __restrict__ aggm,
    const float* __restrict__ W1relT, const float* __restrict__ brel1,
    const float* __restrict__ W1rootT, const float* __restrict__ W2T,
    const float* __restrict__ brel2,
    unsigned short* __restrict__ hrb, float* __restrict__ hro, int N)
{
    __shared__ float A[64 * 65];
    int t = threadIdx.x;
    int lane = t & 63;
    int fbase = __builtin_amdgcn_readfirstlane((t >> 6) * 16);
    int n0 = blockIdx.x * 64;
    int rem = N - n0; if (rem > 64) rem = 64;

#define STAGE(SRC)                                                          \
    for (int idx = t; idx < 1024; idx += 256) {                             \
        int m = idx >> 4, c = idx & 15;                                     \
        int srcn = n0 + ((m < rem) ? m : 0);                                \
        float4 v = *(const float4*)((SRC) + (size_t)srcn * 64 + c * 4);     \
        float* dst = &A[m * 65 + c * 4];                                    \
        dst[0] = v.x; dst[1] = v.y; dst[2] = v.z; dst[3] = v.w;             \
    }

#define PHASE(WT_)                                                          \
    _Pragma("unroll 4")                                                     \
    for (int k = 0; k < 64; ++k) {                                          \
        float a = A[lane * 65 + k];                                         \
        const float* wk = (WT_) + k * 64 + fbase;                           \
        float4 w0 = *(const float4*)(wk);                                   \
        float4 w1 = *(const float4*)(wk + 4);                               \
        float4 w2 = *(const float4*)(wk + 8);                               \
        float4 w3 = *(const float4*)(wk + 12);                              \
        acc0.x = fmaf(a, w0.x, acc0.x); acc0.y = fmaf(a, w0.y, acc0.y);     \
        acc0.z = fmaf(a, w0.z, acc0.z); acc0.w = fmaf(a, w0.w, acc0.w);     \
        acc1.x = fmaf(a, w1.x, acc1.x); acc1.y = fmaf(a, w1.y, acc1.y);     \
        acc1.z = fmaf(a, w1.z, acc1.z); acc1.w = fmaf(a, w1.w, acc1.w);     \
        acc2.x = fmaf(a, w2.x, acc2.x); acc2.y = fmaf(a, w2.y, acc2.y);     \
        acc2.z = fmaf(a, w2.z, acc2.z); acc2.w = fmaf(a, w2.w, acc2.w);     \
        acc3.x = fmaf(a, w3.x, acc3.x); acc3.y = fmaf(a, w3.y, acc3.y);     \
        acc3.z = fmaf(a, w3.z, acc3.z); acc3.w = fmaf(a, w3.w, acc3.w);     \
    }

    // ---- phase 1: acc = b1 + aggm @ Wrel1^T (f-slice) ----
    STAGE(aggm)
    float4 acc0 = *(const float4*)(brel1 + fbase);
    float4 acc1 = *(const float4*)(brel1 + fbase + 4);
    float4 acc2 = *(const float4*)(brel1 + fbase + 8);
    float4 acc3 = *(const float4*)(brel1 + fbase + 12);
    __syncthreads();
    PHASE(W1relT)
    __syncthreads();

    // ---- phase 2: acc += x @ Wroot1^T ; h = sigmoid(acc) ----
    STAGE(x)
    __syncthreads();
    PHASE(W1rootT)
    acc0.x = 1.f / (1.f + __expf(-acc0.x)); acc0.y = 1.f / (1.f + __expf(-acc0.y));
    acc0.z = 1.f / (1.f + __expf(-acc0.z)); acc0.w = 1.f / (1.f + __expf(-acc0.w));
    acc1.x = 1.f / (1.f + __expf(-acc1.x)); acc1.y = 1.f / (1.f + __expf(-acc1.y));
    acc1.z = 1.f / (1.f + __expf(-acc1.z)); acc1.w = 1.f / (1.f + __expf(-acc1.w));
    acc2.x = 1.f / (1.f + __expf(-acc2.x)); acc2.y = 1.f / (1.f + __expf(-acc2.y));
    acc2.z = 1.f / (1.f + __expf(-acc2.z)); acc2.w = 1.f / (1.f + __expf(-acc2.w));
    acc3.x = 1.f / (1.f + __expf(-acc3.x)); acc3.y = 1.f / (1.f + __expf(-acc3.y));
    acc3.z = 1.f / (1.f + __expf(-acc3.z)); acc3.w = 1.f / (1.f + __expf(-acc3.w));
    __syncthreads();

    // ---- h -> LDS tile ----
    {
        float* hrow = &A[lane * 65 + fbase];
        hrow[0] = acc0.x; hrow[1] = acc0.y; hrow[2] = acc0.z; hrow[3] = acc0.w;
        hrow[4] = acc1.x; hrow[5] = acc1.y; hrow[6] = acc1.z; hrow[7] = acc1.w;
        hrow[8] = acc2.x; hrow[9] = acc2.y; hrow[10] = acc2.z; hrow[11] = acc2.w;
        hrow[12] = acc3.x; hrow[13] = acc3.y; hrow[14] = acc3.z; hrow[15] = acc3.w;
    }
    __syncthreads();

    // ---- phase 3: out2[j-slice] = h @ W2T (+b2 for j>=32) ----
    if (fbase < 32) {
        acc0 = make_float4(0.f, 0.f, 0.f, 0.f);
        acc1 = acc0; acc2 = acc0; acc3 = acc0;
    } else {
        acc0 = *(const float4*)(brel2 + fbase - 32);
        acc1 = *(const float4*)(brel2 + fbase - 28);
        acc2 = *(const float4*)(brel2 + fbase - 24);
        acc3 = *(const float4*)(brel2 + fbase - 20);
    }
    PHASE(W2T)
    __syncthreads();

    // ---- out2 -> LDS, then coalesced global write (hr as bf16) ----
    {
        float* orow = &A[lane * 65 + fbase];
        orow[0] = acc0.x; orow[1] = acc0.y; orow[2] = acc0.z; orow[3] = acc0.w;
        orow[4] = acc1.x; orow[5] = acc1.y; orow[6] = acc1.z; orow[7] = acc1.w;
        orow[8] = acc2.x; orow[9] = acc2.y; orow[10] = acc2.z; orow[11] = acc2.w;
        orow[12] = acc3.x; orow[13] = acc3.y; orow[14] = acc3.z; orow[15] = acc3.w;
    }
    __syncthreads();
    for (int idx = t; idx < 1024; idx += 256) {
        int m = idx >> 4, c = idx & 15;
        if (m < rem) {
            const float* src = &A[m * 65 + c * 4];
            if (c < 8) {
                ushort4 v;
                v.x = f2bf(src[0]); v.y = f2bf(src[1]);
                v.z = f2bf(src[2]); v.w = f2bf(src[3]);
                *(ushort4*)(hrb + (size_t)(n0 + m) * 32 + c * 4) = v;
            } else {
                float4 v = make_float4(src[0], src[1], src[2], src[3]);
                *(float4*)(hro + (size_t)(n0 + m) * 32 + (c - 8) * 4) = v;
            }
        }
    }
#undef STAGE
#undef PHASE
}

// ---------------- gather2 + epilogue: out = agg2/deg + hro -------------------
__global__ __launch_bounds__(256) void gather2(
    const unsigned short* __restrict__ hrb, const float* __restrict__ hro,
    const int2* __restrict__ csr, const int* __restrict__ base,
    const int* __restrict__ deg, float* __restrict__ out, int N)
{
    int lane = threadIdx.x & 63;
    int j = lane & 31, half = lane >> 5;
    int wid = blockIdx.x * 4 + (threadIdx.x >> 6);
    int stride = gridDim.x * 4;
    for (int n = wid; n < N; n += stride) {
        int b = __builtin_amdgcn_readfirstlane(base[n]);
        int dg = __builtin_amdgcn_readfirstlane(deg[n]);
        float a0 = 0.f, a1 = 0.f, a2 = 0.f, a3 = 0.f;
        int i = b + half, e = b + dg;
        for (; i + 8 <= e + half; i += 8) {
            int2 r0 = csr[i], r1 = csr[i + 2], r2 = csr[i + 4], r3 = csr[i + 6];
            a0 = fmaf(__int_as_float(r0.y), bf2f(hrb[(size_t)r0.x * 32 + j]), a0);
            a1 = fmaf(__int_as_float(r1.y), bf2f(hrb[(size_t)r1.x * 32 + j]), a1);
            a2 = fmaf(__int_as_float(r2.y), bf2f(hrb[(size_t)r2.x * 32 + j]), a2);
            a3 = fmaf(__int_as_float(r3.y), bf2f(hrb[(size_t)r3.x * 32 + j]), a3);
        }
        for (; i < e; i += 2) {
            int2 r = csr[i];
            a0 = fmaf(__int_as_float(r.y), bf2f(hrb[(size_t)r.x * 32 + j]), a0);
        }
        float acc = (a0 + a1) + (a2 + a3);
        acc += __shfl_xor(acc, 32);
        if (half == 0) {
            float inv = 1.0f / fmaxf((float)dg, 1.0f);
            out[(size_t)n * 32 + j] = acc * inv + hro[(size_t)n * 32 + j];
        }
    }
}

extern "C" void kernel_launch(void* const* d_in, const int* in_sizes, int n_in,
                              void* d_out, int out_size, void* d_ws, size_t ws_size,
                              hipStream_t stream) {
    const float* x      = (const float*)d_in[0];
    const void*  ei_raw = d_in[1];
    const float* ea     = (const float*)d_in[2];
    const float* Wrel1  = (const float*)d_in[3];
    const float* brel1  = (const float*)d_in[4];
    const float* Wroot1 = (const float*)d_in[5];
    const float* Wrel2  = (const float*)d_in[6];
    const float* brel2  = (const float*)d_in[7];
    const float* Wroot2 = (const float*)d_in[8];
    float* out = (float*)d_out;

    const int N = in_sizes[0] / NF;     // 100000
    const int E = in_sizes[2];          // 1000000

    // workspace layout
    long long* csr = (long long*)d_ws;              // E (8 MB)
    int*   deg     = (int*)(csr + E);               // N
    int*   base    = deg + N;                       // N
    int*   bsums   = base + N;                      // 256
    int*   flag    = bsums + 256;                   // 1 (+3 pad)
    int2*  dr      = (int2*)(flag + 4);             // E (8 MB) packed (dst,rank)
    float* aggm    = (float*)(dr + E);              // N*64 fp32
    float* hro     = aggm + (size_t)N * 64;         // N*32 fp32
    float* W1relT  = hro + (size_t)N * 32;          // 4096
    float* W1rootT = W1relT + 4096;                 // 4096
    float* W2T     = W1rootT + 4096;                // 4096
    unsigned short* xb  = (unsigned short*)(W2T + 4096);  // N*64 bf16
    unsigned short* hrb = xb + (size_t)N * 64;            // N*32 bf16

    const int nb1 = (N + 1023) / 1024;
    const int ebq = (E + 1023) / 1024;              // blocks for 4-edge/thread

    hipMemsetAsync(deg, 0, (size_t)N * sizeof(int), stream);
    detect_i64<<<1, 256, 0, stream>>>((const unsigned*)ei_raw, flag, E);
    wprep<<<1, 256, 0, stream>>>(Wrel1, Wroot1, Wrel2, Wroot2, W1relT, W1rootT, W2T);
    xbf16<<<2048, 256, 0, stream>>>(x, xb, (long long)N * 16);
    hist<<<ebq, 256, 0, stream>>>(ei_raw, flag, deg, dr, E);
    scan_k1<<<nb1, 1024, 0, stream>>>(deg, base, bsums, N);
    scan_k2<<<1, 256, 0, stream>>>(bsums, nb1);
    scan_k3<<<nb1, 1024, 0, stream>>>(base, bsums, N);
    fill_csr<<<ebq, 256, 0, stream>>>(ei_raw, flag, ea, dr, base, csr, E);

    gather1<<<2048, 256, 0, stream>>>(xb, (const int2*)csr, base, deg, aggm, N);
    node_fused<<<(N + 63) / 64, 256, 0, stream>>>(x, aggm, W1relT, brel1, W1rootT,
                                                  W2T, brel2, hrb, hro, N);
    gather2<<<2048, 256, 0, stream>>>(hrb, hro, (const int2*)csr, base, deg, out, N);
}

// Round 14
// 174.626 us; speedup vs baseline: 1.3350x; 1.3350x over previous
//
#include <hip/hip_runtime.h>
#include <hip/hip_bf16.h>

// GraphConv x2 via dst-sorted CSR gather.
// CSR build with ZERO global returning atomics (R13 post-mortem: returning
// global atomics cap ~22/ns chip-wide; hist was 46us):
//   p1:   per-block coarse histogram (bucket=dst>>7) via LDS atomics
//   scan: flat exclusive scan over hb[C][B1] (192k entries)
//   p3:   scatter edges to bucket-partitioned part[] (LDS returning atomics)
//   p4:   per-bucket block: local deg count + 128-scan -> deg/base/csr
// Compute: gather1 (bf16 x), node_fused (lane=node, scalar weights),
//          gather2 (bf16 hr). prep fuses detect+wprep+xbf16.

#define NF 64
#define CSHIFT 7
#define CMASK 127
#define CMAX 1024   // supports N <= 131072

__device__ __forceinline__ unsigned short f2bf(float f) {
    __hip_bfloat16 h = __float2bfloat16(f);
    return *reinterpret_cast<unsigned short*>(&h);
}
__device__ __forceinline__ float bf2f(unsigned short u) {
    return __uint_as_float((unsigned int)u << 16);
}

// ---- prep: block0 = dtype detect; block1 = weight transpose; rest = x->bf16
__global__ __launch_bounds__(256) void prep(
    const unsigned* __restrict__ raw, int* __restrict__ flag, int E,
    const float* __restrict__ Wrel1, const float* __restrict__ Wroot1,
    const float* __restrict__ Wrel2, const float* __restrict__ Wroot2,
    float* __restrict__ W1relT, float* __restrict__ W1rootT, float* __restrict__ W2T,
    const float* __restrict__ x, unsigned short* __restrict__ xb, long long n4)
{
    if (blockIdx.x == 0) {
        __shared__ unsigned red[256];
        unsigned v = 0;
        int lim = (E < 4096) ? E : 4096;
        for (int i = threadIdx.x; i < lim; i += 256) v |= raw[2 * i + 1];
        red[threadIdx.x] = v;
        __syncthreads();
        for (int s = 128; s > 0; s >>= 1) {
            if (threadIdx.x < s) red[threadIdx.x] |= red[threadIdx.x + s];
            __syncthreads();
        }
        if (threadIdx.x == 0) *flag = (red[0] == 0) ? 1 : 0;
    } else if (blockIdx.x == 1) {
        int t = threadIdx.x;
        for (int i = t; i < 4096; i += 256) {
            int f = i >> 6, k = i & 63;
            W1relT[k * 64 + f]  = Wrel1[f * 64 + k];
            W1rootT[k * 64 + f] = Wroot1[f * 64 + k];
            W2T[k * 64 + f] = (f < 32) ? Wrel2[f * 64 + k] : Wroot2[(f - 32) * 64 + k];
        }
    } else {
        long long i = (long long)(blockIdx.x - 2) * 256 + threadIdx.x;
        long long stride = (long long)(gridDim.x - 2) * 256;
        for (; i < n4; i += stride) {
            float4 v = *(const float4*)(x + i * 4);
            ushort4 o;
            o.x = f2bf(v.x); o.y = f2bf(v.y); o.z = f2bf(v.z); o.w = f2bf(v.w);
            *(ushort4*)(xb + i * 4) = o;
        }
    }
}

// ---- p1: per-block coarse histogram into hb[c*B1 + blk] --------------------
__global__ __launch_bounds__(1024) void p1_hist(const void* __restrict__ raw,
                                                const int* __restrict__ flag,
                                                int* __restrict__ hb,
                                                int E, int C, int B1) {
    __shared__ int cnt[CMAX];
    int t = threadIdx.x;
    for (int i = t; i < C; i += 1024) cnt[i] = 0;
    __syncthreads();
    int fl = *flag;
    int ebase = blockIdx.x * 4096;
#pragma unroll
    for (int j = 0; j < 4; ++j) {
        int e = ebase + j * 1024 + t;
        if (e < E) {
            int d = fl ? (int)((const long long*)raw)[E + e] : ((const int*)raw)[E + e];
            atomicAdd(&cnt[d >> CSHIFT], 1);      // LDS, non-returning
        }
    }
    __syncthreads();
    for (int i = t; i < C; i += 1024) hb[i * B1 + blockIdx.x] = cnt[i];
}

// ---- flat exclusive scan over M elements (3 kernels, 1024-wide) -------------
__global__ __launch_bounds__(1024) void scan_k1(const int* __restrict__ in,
                                                int* __restrict__ out,
                                                int* __restrict__ bsums, int M) {
    __shared__ int tmp[1024];
    int tid = threadIdx.x;
    int i = blockIdx.x * 1024 + tid;
    int v = (i < M) ? in[i] : 0;
    tmp[tid] = v;
    __syncthreads();
    for (int off = 1; off < 1024; off <<= 1) {
        int t = (tid >= off) ? tmp[tid - off] : 0;
        __syncthreads();
        tmp[tid] += t;
        __syncthreads();
    }
    if (i < M) out[i] = tmp[tid] - v;
    if (tid == 1023) bsums[blockIdx.x] = tmp[tid];
}

__global__ __launch_bounds__(1024) void scan_k2(int* __restrict__ bsums, int nb) {
    __shared__ int tmp[1024];
    int tid = threadIdx.x;
    int v = (tid < nb) ? bsums[tid] : 0;
    tmp[tid] = v;
    __syncthreads();
    for (int off = 1; off < 1024; off <<= 1) {
        int t = (tid >= off) ? tmp[tid - off] : 0;
        __syncthreads();
        tmp[tid] += t;
        __syncthreads();
    }
    if (tid < nb) bsums[tid] = tmp[tid] - v;
}

__global__ __launch_bounds__(1024) void scan_k3(int* __restrict__ out,
                                                const int* __restrict__ bsums, int M) {
    int i = blockIdx.x * 1024 + threadIdx.x;
    if (i >= M) return;
    out[i] += bsums[blockIdx.x];
}

// ---- p3: scatter edges to bucket-partitioned part[] (LDS returning atomics) -
__global__ __launch_bounds__(1024) void p3_scatter(const void* __restrict__ raw,
                                                   const int* __restrict__ flag,
                                                   const float* __restrict__ ea,
                                                   const int* __restrict__ off,
                                                   long long* __restrict__ part,
                                                   int E, int C, int B1) {
    __shared__ int lcur[CMAX];
    int t = threadIdx.x;
    for (int i = t; i < C; i += 1024) lcur[i] = off[i * B1 + blockIdx.x];
    __syncthreads();
    int fl = *flag;
    int ebase = blockIdx.x * 4096;
#pragma unroll
    for (int j = 0; j < 4; ++j) {
        int e = ebase + j * 1024 + t;
        if (e < E) {
            int s, d;
            if (fl) { const long long* p = (const long long*)raw; s = (int)p[e]; d = (int)p[E + e]; }
            else    { const int* p = (const int*)raw; s = p[e]; d = p[E + e]; }
            float w = ea[e];
            int slot = atomicAdd(&lcur[d >> CSHIFT], 1);   // LDS, returning (fast)
            long long pk = (unsigned int)(s | ((d & CMASK) << 20))
                         | ((long long)__float_as_int(w) << 32);
            part[slot] = pk;
        }
    }
}

// ---- p4: per-bucket exact grouping; writes deg, base, csr -------------------
__global__ __launch_bounds__(256) void p4_build(const int* __restrict__ off,
                                                const long long* __restrict__ part,
                                                int2* __restrict__ csr,
                                                int* __restrict__ deg,
                                                int* __restrict__ base,
                                                int E, int N, int C, int B1) {
    __shared__ int ldeg[128], tmp[128], lcur[128];
    int c = blockIdx.x, t = threadIdx.x;
    int bstart = off[c * B1];
    int bend = (c + 1 < C) ? off[(c + 1) * B1] : E;
    if (t < 128) ldeg[t] = 0;
    __syncthreads();
    for (int i = bstart + t; i < bend; i += 256) {
        int lo = (int)part[i];
        atomicAdd(&ldeg[(lo >> 20) & CMASK], 1);           // LDS
    }
    __syncthreads();
    if (t < 128) tmp[t] = ldeg[t];
    __syncthreads();
    for (int o = 1; o < 128; o <<= 1) {
        int v = (t < 128 && t >= o) ? tmp[t - o] : 0;
        __syncthreads();
        if (t < 128) tmp[t] += v;
        __syncthreads();
    }
    if (t < 128) {
        int ex = tmp[t] - ldeg[t];                         // exclusive
        lcur[t] = ex;
        int n = (c << CSHIFT) + t;
        if (n < N) { deg[n] = ldeg[t]; base[n] = bstart + ex; }
    }
    __syncthreads();
    for (int i = bstart + t; i < bend; i += 256) {
        long long pk = part[i];
        int lo = (int)pk;
        int r = atomicAdd(&lcur[(lo >> 20) & CMASK], 1);   // LDS, returning
        csr[bstart + r] = make_int2(lo & 0xFFFFF, (int)(pk >> 32));
    }
}

// ---- gather1: aggm[n] = (sum_e w*xb[src])/max(deg,1) ------------------------
__global__ __launch_bounds__(256) void gather1(
    const unsigned short* __restrict__ xb, const int2* __restrict__ csr,
    const int* __restrict__ base, const int* __restrict__ deg,
    float* __restrict__ aggm, int N)
{
    int lane = threadIdx.x & 63;
    int wid = blockIdx.x * 4 + (threadIdx.x >> 6);
    int stride = gridDim.x * 4;
    for (int n = wid; n < N; n += stride) {
        int b = __builtin_amdgcn_readfirstlane(base[n]);
        int dg = __builtin_amdgcn_readfirstlane(deg[n]);
        float acc0 = 0.f, acc1 = 0.f, acc2 = 0.f, acc3 = 0.f;
        int i = b, e = b + dg;
        for (; i + 8 <= e; i += 8) {
            int2 r0 = csr[i], r1 = csr[i + 1], r2 = csr[i + 2], r3 = csr[i + 3];
            int2 r4 = csr[i + 4], r5 = csr[i + 5], r6 = csr[i + 6], r7 = csr[i + 7];
            float v0 = bf2f(xb[(size_t)r0.x * 64 + lane]);
            float v1 = bf2f(xb[(size_t)r1.x * 64 + lane]);
            float v2 = bf2f(xb[(size_t)r2.x * 64 + lane]);
            float v3 = bf2f(xb[(size_t)r3.x * 64 + lane]);
            float v4 = bf2f(xb[(size_t)r4.x * 64 + lane]);
            float v5 = bf2f(xb[(size_t)r5.x * 64 + lane]);
            float v6 = bf2f(xb[(size_t)r6.x * 64 + lane]);
            float v7 = bf2f(xb[(size_t)r7.x * 64 + lane]);
            acc0 = fmaf(__int_as_float(r0.y), v0, acc0);
            acc1 = fmaf(__int_as_float(r1.y), v1, acc1);
            acc2 = fmaf(__int_as_float(r2.y), v2, acc2);
            acc3 = fmaf(__int_as_float(r3.y), v3, acc3);
            acc0 = fmaf(__int_as_float(r4.y), v4, acc0);
            acc1 = fmaf(__int_as_float(r5.y), v5, acc1);
            acc2 = fmaf(__int_as_float(r6.y), v6, acc2);
            acc3 = fmaf(__int_as_float(r7.y), v7, acc3);
        }
        for (; i + 4 <= e; i += 4) {
            int2 r0 = csr[i], r1 = csr[i + 1], r2 = csr[i + 2], r3 = csr[i + 3];
            acc0 = fmaf(__int_as_float(r0.y), bf2f(xb[(size_t)r0.x * 64 + lane]), acc0);
            acc1 = fmaf(__int_as_float(r1.y), bf2f(xb[(size_t)r1.x * 64 + lane]), acc1);
            acc2 = fmaf(__int_as_float(r2.y), bf2f(xb[(size_t)r2.x * 64 + lane]), acc2);
            acc3 = fmaf(__int_as_float(r3.y), bf2f(xb[(size_t)r3.x * 64 + lane]), acc3);
        }
        for (; i < e; ++i) {
            int2 r = csr[i];
            acc0 = fmaf(__int_as_float(r.y), bf2f(xb[(size_t)r.x * 64 + lane]), acc0);
        }
        float inv = 1.0f / fmaxf((float)dg, 1.0f);
        aggm[(size_t)n * 64 + lane] = ((acc0 + acc1) + (acc2 + acc3)) * inv;
    }
}

// ---- node_fused: lane=node, scalar weights, LDS act tile stride 65 ----------
__global__ __launch_bounds__(256) void node_fused(
    const float* __restrict__ x, const float* __restrict__ aggm,
    const float* __restrict__ W1relT, const float* __restrict__ brel1,
    const float* __restrict__ W1rootT, const float* __restrict__ W2T,
    const float* __restrict__ brel2,
    unsigned short* __restrict__ hrb, float* __restrict__ hro, int N)
{
    __shared__ float A[64 * 65];
    int t = threadIdx.x;
    int lane = t & 63;
    int fbase = __builtin_amdgcn_readfirstlane((t >> 6) * 16);
    int n0 = blockIdx.x * 64;
    int rem = N - n0; if (rem > 64) rem = 64;

#define STAGE(SRC)                                                          \
    for (int idx = t; idx < 1024; idx += 256) {                             \
        int m = idx >> 4, c = idx & 15;                                     \
        int srcn = n0 + ((m < rem) ? m : 0);                                \
        float4 v = *(const float4*)((SRC) + (size_t)srcn * 64 + c * 4);     \
        float* dst = &A[m * 65 + c * 4];                                    \
        dst[0] = v.x; dst[1] = v.y; dst[2] = v.z; dst[3] = v.w;             \
    }

#define PHASE(WT_)                                                          \
    _Pragma("unroll 4")                                                     \
    for (int k = 0; k < 64; ++k) {                                          \
        float a = A[lane * 65 + k];                                         \
        const float* wk = (WT_) + k * 64 + fbase;                           \
        float4 w0 = *(const float4*)(wk);                                   \
        float4 w1 = *(const float4*)(wk + 4);                               \
        float4 w2 = *(const float4*)(wk + 8);                               \
        float4 w3 = *(const float4*)(wk + 12);                              \
        acc0.x = fmaf(a, w0.x, acc0.x); acc0.y = fmaf(a, w0.y, acc0.y);     \
        acc0.z = fmaf(a, w0.z, acc0.z); acc0.w = fmaf(a, w0.w, acc0.w);     \
        acc1.x = fmaf(a, w1.x, acc1.x); acc1.y = fmaf(a, w1.y, acc1.y);     \
        acc1.z = fmaf(a, w1.z, acc1.z); acc1.w = fmaf(a, w1.w, acc1.w);     \
        acc2.x = fmaf(a, w2.x, acc2.x); acc2.y = fmaf(a, w2.y, acc2.y);     \
        acc2.z = fmaf(a, w2.z, acc2.z); acc2.w = fmaf(a, w2.w, acc2.w);     \
        acc3.x = fmaf(a, w3.x, acc3.x); acc3.y = fmaf(a, w3.y, acc3.y);     \
        acc3.z = fmaf(a, w3.z, acc3.z); acc3.w = fmaf(a, w3.w, acc3.w);     \
    }

    STAGE(aggm)
    float4 acc0 = *(const float4*)(brel1 + fbase);
    float4 acc1 = *(const float4*)(brel1 + fbase + 4);
    float4 acc2 = *(const float4*)(brel1 + fbase + 8);
    float4 acc3 = *(const float4*)(brel1 + fbase + 12);
    __syncthreads();
    PHASE(W1relT)
    __syncthreads();

    STAGE(x)
    __syncthreads();
    PHASE(W1rootT)
    acc0.x = 1.f / (1.f + __expf(-acc0.x)); acc0.y = 1.f / (1.f + __expf(-acc0.y));
    acc0.z = 1.f / (1.f + __expf(-acc0.z)); acc0.w = 1.f / (1.f + __expf(-acc0.w));
    acc1.x = 1.f / (1.f + __expf(-acc1.x)); acc1.y = 1.f / (1.f + __expf(-acc1.y));
    acc1.z = 1.f / (1.f + __expf(-acc1.z)); acc1.w = 1.f / (1.f + __expf(-acc1.w));
    acc2.x = 1.f / (1.f + __expf(-acc2.x)); acc2.y = 1.f / (1.f + __expf(-acc2.y));
    acc2.z = 1.f / (1.f + __expf(-acc2.z)); acc2.w = 1.f / (1.f + __expf(-acc2.w));
    acc3.x = 1.f / (1.f + __expf(-acc3.x)); acc3.y = 1.f / (1.f + __expf(-acc3.y));
    acc3.z = 1.f / (1.f + __expf(-acc3.z)); acc3.w = 1.f / (1.f + __expf(-acc3.w));
    __syncthreads();

    {
        float* hrow = &A[lane * 65 + fbase];
        hrow[0] = acc0.x; hrow[1] = acc0.y; hrow[2] = acc0.z; hrow[3] = acc0.w;
        hrow[4] = acc1.x; hrow[5] = acc1.y; hrow[6] = acc1.z; hrow[7] = acc1.w;
        hrow[8] = acc2.x; hrow[9] = acc2.y; hrow[10] = acc2.z; hrow[11] = acc2.w;
        hrow[12] = acc3.x; hrow[13] = acc3.y; hrow[14] = acc3.z; hrow[15] = acc3.w;
    }
    __syncthreads();

    if (fbase < 32) {
        acc0 = make_float4(0.f, 0.f, 0.f, 0.f);
        acc1 = acc0; acc2 = acc0; acc3 = acc0;
    } else {
        acc0 = *(const float4*)(brel2 + fbase - 32);
        acc1 = *(const float4*)(brel2 + fbase - 28);
        acc2 = *(const float4*)(brel2 + fbase - 24);
        acc3 = *(const float4*)(brel2 + fbase - 20);
    }
    PHASE(W2T)
    __syncthreads();

    {
        float* orow = &A[lane * 65 + fbase];
        orow[0] = acc0.x; orow[1] = acc0.y; orow[2] = acc0.z; orow[3] = acc0.w;
        orow[4] = acc1.x; orow[5] = acc1.y; orow[6] = acc1.z; orow[7] = acc1.w;
        orow[8] = acc2.x; orow[9] = acc2.y; orow[10] = acc2.z; orow[11] = acc2.w;
        orow[12] = acc3.x; orow[13] = acc3.y; orow[14] = acc3.z; orow[15] = acc3.w;
    }
    __syncthreads();
    for (int idx = t; idx < 1024; idx += 256) {
        int m = idx >> 4, c = idx & 15;
        if (m < rem) {
            const float* src = &A[m * 65 + c * 4];
            if (c < 8) {
                ushort4 v;
                v.x = f2bf(src[0]); v.y = f2bf(src[1]);
                v.z = f2bf(src[2]); v.w = f2bf(src[3]);
                *(ushort4*)(hrb + (size_t)(n0 + m) * 32 + c * 4) = v;
            } else {
                float4 v = make_float4(src[0], src[1], src[2], src[3]);
                *(float4*)(hro + (size_t)(n0 + m) * 32 + (c - 8) * 4) = v;
            }
        }
    }
#undef STAGE
#undef PHASE
}

// ---- gather2 + epilogue: out = agg2/deg + hro -------------------------------
__global__ __launch_bounds__(256) void gather2(
    const unsigned short* __restrict__ hrb, const float* __restrict__ hro,
    const int2* __restrict__ csr, const int* __restrict__ base,
    const int* __restrict__ deg, float* __restrict__ out, int N)
{
    int lane = threadIdx.x & 63;
    int j = lane & 31, half = lane >> 5;
    int wid = blockIdx.x * 4 + (threadIdx.x >> 6);
    int stride = gridDim.x * 4;
    for (int n = wid; n < N; n += stride) {
        int b = __builtin_amdgcn_readfirstlane(base[n]);
        int dg = __builtin_amdgcn_readfirstlane(deg[n]);
        float a0 = 0.f, a1 = 0.f, a2 = 0.f, a3 = 0.f;
        int i = b + half, e = b + dg;
        for (; i + 8 <= e + half; i += 8) {
            int2 r0 = csr[i], r1 = csr[i + 2], r2 = csr[i + 4], r3 = csr[i + 6];
            a0 = fmaf(__int_as_float(r0.y), bf2f(hrb[(size_t)r0.x * 32 + j]), a0);
            a1 = fmaf(__int_as_float(r1.y), bf2f(hrb[(size_t)r1.x * 32 + j]), a1);
            a2 = fmaf(__int_as_float(r2.y), bf2f(hrb[(size_t)r2.x * 32 + j]), a2);
            a3 = fmaf(__int_as_float(r3.y), bf2f(hrb[(size_t)r3.x * 32 + j]), a3);
        }
        for (; i < e; i += 2) {
            int2 r = csr[i];
            a0 = fmaf(__int_as_float(r.y), bf2f(hrb[(size_t)r.x * 32 + j]), a0);
        }
        float acc = (a0 + a1) + (a2 + a3);
        acc += __shfl_xor(acc, 32);
        if (half == 0) {
            float inv = 1.0f / fmaxf((float)dg, 1.0f);
            out[(size_t)n * 32 + j] = acc * inv + hro[(size_t)n * 32 + j];
        }
    }
}

extern "C" void kernel_launch(void* const* d_in, const int* in_sizes, int n_in,
                              void* d_out, int out_size, void* d_ws, size_t ws_size,
                              hipStream_t stream) {
    const float* x      = (const float*)d_in[0];
    const void*  ei_raw = d_in[1];
    const float* ea     = (const float*)d_in[2];
    const float* Wrel1  = (const float*)d_in[3];
    const float* brel1  = (const float*)d_in[4];
    const float* Wroot1 = (const float*)d_in[5];
    const float* Wrel2  = (const float*)d_in[6];
    const float* brel2  = (const float*)d_in[7];
    const float* Wroot2 = (const float*)d_in[8];
    float* out = (float*)d_out;

    const int N = in_sizes[0] / NF;          // 100000
    const int E = in_sizes[2];               // 1000000
    const int C  = (N + CMASK) >> CSHIFT;    // 782 coarse buckets
    const int B1 = (E + 4095) / 4096;        // 245 edge blocks
    const int M  = C * B1;                   // 191590
    const int nbM = (M + 1023) / 1024;       // 188

    // workspace layout
    long long* part = (long long*)d_ws;                 // E (8 MB)
    int2*  csr     = (int2*)(part + E);                 // E (8 MB)
    int*   off     = (int*)(csr + E);                   // M
    int*   bsums   = off + M;                           // nbM (+pad)
    int*   flag    = bsums + 1024;                      // 1 (+3 pad)
    int*   deg     = flag + 4;                          // N
    int*   base    = deg + N;                           // N
    float* aggm    = (float*)(base + N);                // N*64 fp32
    float* hro     = aggm + (size_t)N * 64;             // N*32 fp32
    float* W1relT  = hro + (size_t)N * 32;              // 4096
    float* W1rootT = W1relT + 4096;                     // 4096
    float* W2T     = W1rootT + 4096;                    // 4096
    unsigned short* xb  = (unsigned short*)(W2T + 4096);  // N*64 bf16
    unsigned short* hrb = xb + (size_t)N * 64;             // N*32 bf16

    prep<<<2048, 256, 0, stream>>>((const unsigned*)ei_raw, flag, E,
                                   Wrel1, Wroot1, Wrel2, Wroot2,
                                   W1relT, W1rootT, W2T, x, xb, (long long)N * 16);
    p1_hist<<<B1, 1024, 0, stream>>>(ei_raw, flag, off /*unused*/, E, C, B1);
    // NOTE: p1 writes histogram into 'off' buffer? No — use part as hb? Keep clean:
    // (hb stored in csr buffer temporarily — csr is dead until p4)
    // Re-launch with proper buffers below.
    // -- The calls above/below are ordered; p1 actually writes hb into (int*)csr.
    p1_hist<<<B1, 1024, 0, stream>>>(ei_raw, flag, (int*)csr, E, C, B1);
    scan_k1<<<nbM, 1024, 0, stream>>>((int*)csr, off, bsums, M);
    scan_k2<<<1, 1024, 0, stream>>>(bsums, nbM);
    scan_k3<<<nbM, 1024, 0, stream>>>(off, bsums, M);
    p3_scatter<<<B1, 1024, 0, stream>>>(ei_raw, flag, ea, off, part, E, C, B1);
    p4_build<<<C, 256, 0, stream>>>(off, part, csr, deg, base, E, N, C, B1);

    gather1<<<2048, 256, 0, stream>>>(xb, csr, base, deg, aggm, N);
    node_fused<<<(N + 63) / 64, 256, 0, stream>>>(x, aggm, W1relT, brel1, W1rootT,
                                                  W2T, brel2, hrb, hro, N);
    gather2<<<2048, 256, 0, stream>>>(hrb, hro, csr, base, deg, out, N);
}

// Round 15
// 170.758 us; speedup vs baseline: 1.3652x; 1.0226x over previous
//
#include <hip/hip_runtime.h>
#include <hip/hip_bf16.h>

// GraphConv x2 via dst-sorted CSR gather.
// CSR build with ZERO global returning atomics (LDS-atomic 4-phase, R14):
//   p1 coarse hist -> flat scan -> p3 bucket scatter -> p4 per-bucket build.
// Compute: gather1 (bf16 x -> bf16 aggm), node_fused v3 (phases 1+2 merged,
// manual 4-deep a-ILP; R14 post-mortem: VGPR=16 showed the compiler refused
// unroll ILP -> serial ds_read->FMA chain at 45us), gather2 (bf16 hr).

#define NF 64
#define CSHIFT 7
#define CMASK 127
#define CMAX 1024   // supports N <= 131072

__device__ __forceinline__ unsigned short f2bf(float f) {
    __hip_bfloat16 h = __float2bfloat16(f);
    return *reinterpret_cast<unsigned short*>(&h);
}
__device__ __forceinline__ float bf2f(unsigned short u) {
    return __uint_as_float((unsigned int)u << 16);
}

// ---- prep: block0 = dtype detect; block1 = weight transpose; rest = x->bf16
__global__ __launch_bounds__(256) void prep(
    const unsigned* __restrict__ raw, int* __restrict__ flag, int E,
    const float* __restrict__ Wrel1, const float* __restrict__ Wroot1,
    const float* __restrict__ Wrel2, const float* __restrict__ Wroot2,
    float* __restrict__ W1relT, float* __restrict__ W1rootT, float* __restrict__ W2T,
    const float* __restrict__ x, unsigned short* __restrict__ xb, long long n4)
{
    if (blockIdx.x == 0) {
        __shared__ unsigned red[256];
        unsigned v = 0;
        int lim = (E < 4096) ? E : 4096;
        for (int i = threadIdx.x; i < lim; i += 256) v |= raw[2 * i + 1];
        red[threadIdx.x] = v;
        __syncthreads();
        for (int s = 128; s > 0; s >>= 1) {
            if (threadIdx.x < s) red[threadIdx.x] |= red[threadIdx.x + s];
            __syncthreads();
        }
        if (threadIdx.x == 0) *flag = (red[0] == 0) ? 1 : 0;
    } else if (blockIdx.x == 1) {
        int t = threadIdx.x;
        for (int i = t; i < 4096; i += 256) {
            int f = i >> 6, k = i & 63;
            W1relT[k * 64 + f]  = Wrel1[f * 64 + k];
            W1rootT[k * 64 + f] = Wroot1[f * 64 + k];
            W2T[k * 64 + f] = (f < 32) ? Wrel2[f * 64 + k] : Wroot2[(f - 32) * 64 + k];
        }
    } else {
        long long i = (long long)(blockIdx.x - 2) * 256 + threadIdx.x;
        long long stride = (long long)(gridDim.x - 2) * 256;
        for (; i < n4; i += stride) {
            float4 v = *(const float4*)(x + i * 4);
            ushort4 o;
            o.x = f2bf(v.x); o.y = f2bf(v.y); o.z = f2bf(v.z); o.w = f2bf(v.w);
            *(ushort4*)(xb + i * 4) = o;
        }
    }
}

// ---- p1: per-block coarse histogram into hb[c*B1 + blk] --------------------
__global__ __launch_bounds__(1024) void p1_hist(const void* __restrict__ raw,
                                                const int* __restrict__ flag,
                                                int* __restrict__ hb,
                                                int E, int C, int B1) {
    __shared__ int cnt[CMAX];
    int t = threadIdx.x;
    for (int i = t; i < C; i += 1024) cnt[i] = 0;
    __syncthreads();
    int fl = *flag;
    int ebase = blockIdx.x * 4096;
#pragma unroll
    for (int j = 0; j < 4; ++j) {
        int e = ebase + j * 1024 + t;
        if (e < E) {
            int d = fl ? (int)((const long long*)raw)[E + e] : ((const int*)raw)[E + e];
            atomicAdd(&cnt[d >> CSHIFT], 1);      // LDS, non-returning
        }
    }
    __syncthreads();
    for (int i = t; i < C; i += 1024) hb[i * B1 + blockIdx.x] = cnt[i];
}

// ---- flat exclusive scan over M elements (3 kernels, 1024-wide) -------------
__global__ __launch_bounds__(1024) void scan_k1(const int* __restrict__ in,
                                                int* __restrict__ out,
                                                int* __restrict__ bsums, int M) {
    __shared__ int tmp[1024];
    int tid = threadIdx.x;
    int i = blockIdx.x * 1024 + tid;
    int v = (i < M) ? in[i] : 0;
    tmp[tid] = v;
    __syncthreads();
    for (int off = 1; off < 1024; off <<= 1) {
        int t = (tid >= off) ? tmp[tid - off] : 0;
        __syncthreads();
        tmp[tid] += t;
        __syncthreads();
    }
    if (i < M) out[i] = tmp[tid] - v;
    if (tid == 1023) bsums[blockIdx.x] = tmp[tid];
}

__global__ __launch_bounds__(1024) void scan_k2(int* __restrict__ bsums, int nb) {
    __shared__ int tmp[1024];
    int tid = threadIdx.x;
    int v = (tid < nb) ? bsums[tid] : 0;
    tmp[tid] = v;
    __syncthreads();
    for (int off = 1; off < 1024; off <<= 1) {
        int t = (tid >= off) ? tmp[tid - off] : 0;
        __syncthreads();
        tmp[tid] += t;
        __syncthreads();
    }
    if (tid < nb) bsums[tid] = tmp[tid] - v;
}

__global__ __launch_bounds__(1024) void scan_k3(int* __restrict__ out,
                                                const int* __restrict__ bsums, int M) {
    int i = blockIdx.x * 1024 + threadIdx.x;
    if (i >= M) return;
    out[i] += bsums[blockIdx.x];
}

// ---- p3: scatter edges to bucket-partitioned part[] (LDS returning atomics) -
__global__ __launch_bounds__(1024) void p3_scatter(const void* __restrict__ raw,
                                                   const int* __restrict__ flag,
                                                   const float* __restrict__ ea,
                                                   const int* __restrict__ off,
                                                   long long* __restrict__ part,
                                                   int E, int C, int B1) {
    __shared__ int lcur[CMAX];
    int t = threadIdx.x;
    for (int i = t; i < C; i += 1024) lcur[i] = off[i * B1 + blockIdx.x];
    __syncthreads();
    int fl = *flag;
    int ebase = blockIdx.x * 4096;
#pragma unroll
    for (int j = 0; j < 4; ++j) {
        int e = ebase + j * 1024 + t;
        if (e < E) {
            int s, d;
            if (fl) { const long long* p = (const long long*)raw; s = (int)p[e]; d = (int)p[E + e]; }
            else    { const int* p = (const int*)raw; s = p[e]; d = p[E + e]; }
            float w = ea[e];
            int slot = atomicAdd(&lcur[d >> CSHIFT], 1);   // LDS, returning (fast)
            long long pk = (unsigned int)(s | ((d & CMASK) << 20))
                         | ((long long)__float_as_int(w) << 32);
            part[slot] = pk;
        }
    }
}

// ---- p4: per-bucket exact grouping; writes deg, base, csr -------------------
__global__ __launch_bounds__(256) void p4_build(const int* __restrict__ off,
                                                const long long* __restrict__ part,
                                                int2* __restrict__ csr,
                                                int* __restrict__ deg,
                                                int* __restrict__ base,
                                                int E, int N, int C, int B1) {
    __shared__ int ldeg[128], tmp[128], lcur[128];
    int c = blockIdx.x, t = threadIdx.x;
    int bstart = off[c * B1];
    int bend = (c + 1 < C) ? off[(c + 1) * B1] : E;
    if (t < 128) ldeg[t] = 0;
    __syncthreads();
    for (int i = bstart + t; i < bend; i += 256) {
        int lo = (int)part[i];
        atomicAdd(&ldeg[(lo >> 20) & CMASK], 1);           // LDS
    }
    __syncthreads();
    if (t < 128) tmp[t] = ldeg[t];
    __syncthreads();
    for (int o = 1; o < 128; o <<= 1) {
        int v = (t < 128 && t >= o) ? tmp[t - o] : 0;
        __syncthreads();
        if (t < 128) tmp[t] += v;
        __syncthreads();
    }
    if (t < 128) {
        int ex = tmp[t] - ldeg[t];                         // exclusive
        lcur[t] = ex;
        int n = (c << CSHIFT) + t;
        if (n < N) { deg[n] = ldeg[t]; base[n] = bstart + ex; }
    }
    __syncthreads();
    for (int i = bstart + t; i < bend; i += 256) {
        long long pk = part[i];
        int lo = (int)pk;
        int r = atomicAdd(&lcur[(lo >> 20) & CMASK], 1);   // LDS, returning
        csr[bstart + r] = make_int2(lo & 0xFFFFF, (int)(pk >> 32));
    }
}

// ---- gather1: aggb[n] = bf16((sum_e w*xb[src])/max(deg,1)) ------------------
__global__ __launch_bounds__(256) void gather1(
    const unsigned short* __restrict__ xb, const int2* __restrict__ csr,
    const int* __restrict__ base, const int* __restrict__ deg,
    unsigned short* __restrict__ aggb, int N)
{
    int lane = threadIdx.x & 63;
    int wid = blockIdx.x * 4 + (threadIdx.x >> 6);
    int stride = gridDim.x * 4;
    for (int n = wid; n < N; n += stride) {
        int b = __builtin_amdgcn_readfirstlane(base[n]);
        int dg = __builtin_amdgcn_readfirstlane(deg[n]);
        float acc0 = 0.f, acc1 = 0.f, acc2 = 0.f, acc3 = 0.f;
        int i = b, e = b + dg;
        for (; i + 8 <= e; i += 8) {
            int2 r0 = csr[i], r1 = csr[i + 1], r2 = csr[i + 2], r3 = csr[i + 3];
            int2 r4 = csr[i + 4], r5 = csr[i + 5], r6 = csr[i + 6], r7 = csr[i + 7];
            float v0 = bf2f(xb[(size_t)r0.x * 64 + lane]);
            float v1 = bf2f(xb[(size_t)r1.x * 64 + lane]);
            float v2 = bf2f(xb[(size_t)r2.x * 64 + lane]);
            float v3 = bf2f(xb[(size_t)r3.x * 64 + lane]);
            float v4 = bf2f(xb[(size_t)r4.x * 64 + lane]);
            float v5 = bf2f(xb[(size_t)r5.x * 64 + lane]);
            float v6 = bf2f(xb[(size_t)r6.x * 64 + lane]);
            float v7 = bf2f(xb[(size_t)r7.x * 64 + lane]);
            acc0 = fmaf(__int_as_float(r0.y), v0, acc0);
            acc1 = fmaf(__int_as_float(r1.y), v1, acc1);
            acc2 = fmaf(__int_as_float(r2.y), v2, acc2);
            acc3 = fmaf(__int_as_float(r3.y), v3, acc3);
            acc0 = fmaf(__int_as_float(r4.y), v4, acc0);
            acc1 = fmaf(__int_as_float(r5.y), v5, acc1);
            acc2 = fmaf(__int_as_float(r6.y), v6, acc2);
            acc3 = fmaf(__int_as_float(r7.y), v7, acc3);
        }
        for (; i + 4 <= e; i += 4) {
            int2 r0 = csr[i], r1 = csr[i + 1], r2 = csr[i + 2], r3 = csr[i + 3];
            acc0 = fmaf(__int_as_float(r0.y), bf2f(xb[(size_t)r0.x * 64 + lane]), acc0);
            acc1 = fmaf(__int_as_float(r1.y), bf2f(xb[(size_t)r1.x * 64 + lane]), acc1);
            acc2 = fmaf(__int_as_float(r2.y), bf2f(xb[(size_t)r2.x * 64 + lane]), acc2);
            acc3 = fmaf(__int_as_float(r3.y), bf2f(xb[(size_t)r3.x * 64 + lane]), acc3);
        }
        for (; i < e; ++i) {
            int2 r = csr[i];
            acc0 = fmaf(__int_as_float(r.y), bf2f(xb[(size_t)r.x * 64 + lane]), acc0);
        }
        float inv = 1.0f / fmaxf((float)dg, 1.0f);
        aggb[(size_t)n * 64 + lane] = f2bf(((acc0 + acc1) + (acc2 + acc3)) * inv);
    }
}

// ---- node_fused v3: phases 1+2 merged, manual 4-deep a-ILP ------------------
// Tiles: Ag (agg), Xt (x) both [64][65] f32 staged from bf16. Per k:
// 2 LDS b32 + 8 scalar float4 (wave-uniform) + 32 FMA. Column reads at
// stride 65: banks (lane+k)%32 -> 2-way = free.
__global__ __launch_bounds__(256) void node_fused(
    const unsigned short* __restrict__ aggb, const unsigned short* __restrict__ xb,
    const float* __restrict__ W1relT, const float* __restrict__ brel1,
    const float* __restrict__ W1rootT, const float* __restrict__ W2T,
    const float* __restrict__ brel2,
    unsigned short* __restrict__ hrb, float* __restrict__ hro, int N)
{
    __shared__ float Ag[64 * 65];
    __shared__ float Xt[64 * 65];
    int t = threadIdx.x;
    int lane = t & 63;
    int fbase = __builtin_amdgcn_readfirstlane((t >> 6) * 16);
    int n0 = blockIdx.x * 64;
    int rem = N - n0; if (rem > 64) rem = 64;

    // stage both tiles (bf16 -> f32), 8 elems per thread-iter
    for (int idx = t; idx < 512; idx += 256) {
        int m = idx >> 3, c = idx & 7;
        int srcn = n0 + ((m < rem) ? m : 0);
        uint4 va = *(const uint4*)(aggb + (size_t)srcn * 64 + c * 8);
        uint4 vx = *(const uint4*)(xb + (size_t)srcn * 64 + c * 8);
        float* da = &Ag[m * 65 + c * 8];
        float* dx = &Xt[m * 65 + c * 8];
        da[0] = __uint_as_float(va.x << 16); da[1] = __uint_as_float(va.x & 0xffff0000u);
        da[2] = __uint_as_float(va.y << 16); da[3] = __uint_as_float(va.y & 0xffff0000u);
        da[4] = __uint_as_float(va.z << 16); da[5] = __uint_as_float(va.z & 0xffff0000u);
        da[6] = __uint_as_float(va.w << 16); da[7] = __uint_as_float(va.w & 0xffff0000u);
        dx[0] = __uint_as_float(vx.x << 16); dx[1] = __uint_as_float(vx.x & 0xffff0000u);
        dx[2] = __uint_as_float(vx.y << 16); dx[3] = __uint_as_float(vx.y & 0xffff0000u);
        dx[4] = __uint_as_float(vx.z << 16); dx[5] = __uint_as_float(vx.z & 0xffff0000u);
        dx[6] = __uint_as_float(vx.w << 16); dx[7] = __uint_as_float(vx.w & 0xffff0000u);
    }

    float4 acc0 = *(const float4*)(brel1 + fbase);
    float4 acc1 = *(const float4*)(brel1 + fbase + 4);
    float4 acc2 = *(const float4*)(brel1 + fbase + 8);
    float4 acc3 = *(const float4*)(brel1 + fbase + 12);
    __syncthreads();

#define K_STEP12(K, AV, BV)                                                 \
    {                                                                       \
        const float* wr = W1relT + (K) * 64 + fbase;                        \
        const float* wo = W1rootT + (K) * 64 + fbase;                       \
        float4 r0 = *(const float4*)(wr),     r1 = *(const float4*)(wr + 4);\
        float4 r2 = *(const float4*)(wr + 8), r3 = *(const float4*)(wr + 12);\
        float4 o0 = *(const float4*)(wo),     o1 = *(const float4*)(wo + 4);\
        float4 o2 = *(const float4*)(wo + 8), o3 = *(const float4*)(wo + 12);\
        acc0.x = fmaf(AV, r0.x, acc0.x); acc0.y = fmaf(AV, r0.y, acc0.y);   \
        acc0.z = fmaf(AV, r0.z, acc0.z); acc0.w = fmaf(AV, r0.w, acc0.w);   \
        acc1.x = fmaf(AV, r1.x, acc1.x); acc1.y = fmaf(AV, r1.y, acc1.y);   \
        acc1.z = fmaf(AV, r1.z, acc1.z); acc1.w = fmaf(AV, r1.w, acc1.w);   \
        acc2.x = fmaf(AV, r2.x, acc2.x); acc2.y = fmaf(AV, r2.y, acc2.y);   \
        acc2.z = fmaf(AV, r2.z, acc2.z); acc2.w = fmaf(AV, r2.w, acc2.w);   \
        acc3.x = fmaf(AV, r3.x, acc3.x); acc3.y = fmaf(AV, r3.y, acc3.y);   \
        acc3.z = fmaf(AV, r3.z, acc3.z); acc3.w = fmaf(AV, r3.w, acc3.w);   \
        acc0.x = fmaf(BV, o0.x, acc0.x); acc0.y = fmaf(BV, o0.y, acc0.y);   \
        acc0.z = fmaf(BV, o0.z, acc0.z); acc0.w = fmaf(BV, o0.w, acc0.w);   \
        acc1.x = fmaf(BV, o1.x, acc1.x); acc1.y = fmaf(BV, o1.y, acc1.y);   \
        acc1.z = fmaf(BV, o1.z, acc1.z); acc1.w = fmaf(BV, o1.w, acc1.w);   \
        acc2.x = fmaf(BV, o2.x, acc2.x); acc2.y = fmaf(BV, o2.y, acc2.y);   \
        acc2.z = fmaf(BV, o2.z, acc2.z); acc2.w = fmaf(BV, o2.w, acc2.w);   \
        acc3.x = fmaf(BV, o3.x, acc3.x); acc3.y = fmaf(BV, o3.y, acc3.y);   \
        acc3.z = fmaf(BV, o3.z, acc3.z); acc3.w = fmaf(BV, o3.w, acc3.w);   \
    }

    for (int k4 = 0; k4 < 16; ++k4) {
        int kb = k4 * 4;
        float a0 = Ag[lane * 65 + kb + 0], a1 = Ag[lane * 65 + kb + 1];
        float a2 = Ag[lane * 65 + kb + 2], a3 = Ag[lane * 65 + kb + 3];
        float b0 = Xt[lane * 65 + kb + 0], b1 = Xt[lane * 65 + kb + 1];
        float b2 = Xt[lane * 65 + kb + 2], b3 = Xt[lane * 65 + kb + 3];
        K_STEP12(kb + 0, a0, b0)
        K_STEP12(kb + 1, a1, b1)
        K_STEP12(kb + 2, a2, b2)
        K_STEP12(kb + 3, a3, b3)
    }
#undef K_STEP12

    acc0.x = 1.f / (1.f + __expf(-acc0.x)); acc0.y = 1.f / (1.f + __expf(-acc0.y));
    acc0.z = 1.f / (1.f + __expf(-acc0.z)); acc0.w = 1.f / (1.f + __expf(-acc0.w));
    acc1.x = 1.f / (1.f + __expf(-acc1.x)); acc1.y = 1.f / (1.f + __expf(-acc1.y));
    acc1.z = 1.f / (1.f + __expf(-acc1.z)); acc1.w = 1.f / (1.f + __expf(-acc1.w));
    acc2.x = 1.f / (1.f + __expf(-acc2.x)); acc2.y = 1.f / (1.f + __expf(-acc2.y));
    acc2.z = 1.f / (1.f + __expf(-acc2.z)); acc2.w = 1.f / (1.f + __expf(-acc2.w));
    acc3.x = 1.f / (1.f + __expf(-acc3.x)); acc3.y = 1.f / (1.f + __expf(-acc3.y));
    acc3.z = 1.f / (1.f + __expf(-acc3.z)); acc3.w = 1.f / (1.f + __expf(-acc3.w));
    __syncthreads();      // all phase-1/2 reads of Ag done

    // h -> Ag tile
    {
        float* hrow = &Ag[lane * 65 + fbase];
        hrow[0] = acc0.x; hrow[1] = acc0.y; hrow[2] = acc0.z; hrow[3] = acc0.w;
        hrow[4] = acc1.x; hrow[5] = acc1.y; hrow[6] = acc1.z; hrow[7] = acc1.w;
        hrow[8] = acc2.x; hrow[9] = acc2.y; hrow[10] = acc2.z; hrow[11] = acc2.w;
        hrow[12] = acc3.x; hrow[13] = acc3.y; hrow[14] = acc3.z; hrow[15] = acc3.w;
    }
    __syncthreads();

    // phase 3: out2[j-slice] = h @ W2T (+b2 for j>=32)
    if (fbase < 32) {
        acc0 = make_float4(0.f, 0.f, 0.f, 0.f);
        acc1 = acc0; acc2 = acc0; acc3 = acc0;
    } else {
        acc0 = *(const float4*)(brel2 + fbase - 32);
        acc1 = *(const float4*)(brel2 + fbase - 28);
        acc2 = *(const float4*)(brel2 + fbase - 24);
        acc3 = *(const float4*)(brel2 + fbase - 20);
    }

#define K_STEP3(K, AV)                                                      \
    {                                                                       \
        const float* wk = W2T + (K) * 64 + fbase;                           \
        float4 w0 = *(const float4*)(wk),     w1 = *(const float4*)(wk + 4);\
        float4 w2 = *(const float4*)(wk + 8), w3 = *(const float4*)(wk + 12);\
        acc0.x = fmaf(AV, w0.x, acc0.x); acc0.y = fmaf(AV, w0.y, acc0.y);   \
        acc0.z = fmaf(AV, w0.z, acc0.z); acc0.w = fmaf(AV, w0.w, acc0.w);   \
        acc1.x = fmaf(AV, w1.x, acc1.x); acc1.y = fmaf(AV, w1.y, acc1.y);   \
        acc1.z = fmaf(AV, w1.z, acc1.z); acc1.w = fmaf(AV, w1.w, acc1.w);   \
        acc2.x = fmaf(AV, w2.x, acc2.x); acc2.y = fmaf(AV, w2.y, acc2.y);   \
        acc2.z = fmaf(AV, w2.z, acc2.z); acc2.w = fmaf(AV, w2.w, acc2.w);   \
        acc3.x = fmaf(AV, w3.x, acc3.x); acc3.y = fmaf(AV, w3.y, acc3.y);   \
        acc3.z = fmaf(AV, w3.z, acc3.z); acc3.w = fmaf(AV, w3.w, acc3.w);   \
    }

    for (int k4 = 0; k4 < 16; ++k4) {
        int kb = k4 * 4;
        float a0 = Ag[lane * 65 + kb + 0], a1 = Ag[lane * 65 + kb + 1];
        float a2 = Ag[lane * 65 + kb + 2], a3 = Ag[lane * 65 + kb + 3];
        K_STEP3(kb + 0, a0)
        K_STEP3(kb + 1, a1)
        K_STEP3(kb + 2, a2)
        K_STEP3(kb + 3, a3)
    }
#undef K_STEP3

    // out2 -> Xt tile (Ag still holds h; Xt free since the barrier)
    {
        float* orow = &Xt[lane * 65 + fbase];
        orow[0] = acc0.x; orow[1] = acc0.y; orow[2] = acc0.z; orow[3] = acc0.w;
        orow[4] = acc1.x; orow[5] = acc1.y; orow[6] = acc1.z; orow[7] = acc1.w;
        orow[8] = acc2.x; orow[9] = acc2.y; orow[10] = acc2.z; orow[11] = acc2.w;
        orow[12] = acc3.x; orow[13] = acc3.y; orow[14] = acc3.z; orow[15] = acc3.w;
    }
    __syncthreads();
    for (int idx = t; idx < 1024; idx += 256) {
        int m = idx >> 4, c = idx & 15;
        if (m < rem) {
            const float* src = &Xt[m * 65 + c * 4];
            if (c < 8) {
                ushort4 v;
                v.x = f2bf(src[0]); v.y = f2bf(src[1]);
                v.z = f2bf(src[2]); v.w = f2bf(src[3]);
                *(ushort4*)(hrb + (size_t)(n0 + m) * 32 + c * 4) = v;
            } else {
                float4 v = make_float4(src[0], src[1], src[2], src[3]);
                *(float4*)(hro + (size_t)(n0 + m) * 32 + (c - 8) * 4) = v;
            }
        }
    }
}

// ---- gather2 + epilogue: out = agg2/deg + hro -------------------------------
__global__ __launch_bounds__(256) void gather2(
    const unsigned short* __restrict__ hrb, const float* __restrict__ hro,
    const int2* __restrict__ csr, const int* __restrict__ base,
    const int* __restrict__ deg, float* __restrict__ out, int N)
{
    int lane = threadIdx.x & 63;
    int j = lane & 31, half = lane >> 5;
    int wid = blockIdx.x * 4 + (threadIdx.x >> 6);
    int stride = gridDim.x * 4;
    for (int n = wid; n < N; n += stride) {
        int b = __builtin_amdgcn_readfirstlane(base[n]);
        int dg = __builtin_amdgcn_readfirstlane(deg[n]);
        float a0 = 0.f, a1 = 0.f, a2 = 0.f, a3 = 0.f;
        int i = b + half, e = b + dg;
        for (; i + 8 <= e + half; i += 8) {
            int2 r0 = csr[i], r1 = csr[i + 2], r2 = csr[i + 4], r3 = csr[i + 6];
            a0 = fmaf(__int_as_float(r0.y), bf2f(hrb[(size_t)r0.x * 32 + j]), a0);
            a1 = fmaf(__int_as_float(r1.y), bf2f(hrb[(size_t)r1.x * 32 + j]), a1);
            a2 = fmaf(__int_as_float(r2.y), bf2f(hrb[(size_t)r2.x * 32 + j]), a2);
            a3 = fmaf(__int_as_float(r3.y), bf2f(hrb[(size_t)r3.x * 32 + j]), a3);
        }
        for (; i < e; i += 2) {
            int2 r = csr[i];
            a0 = fmaf(__int_as_float(r.y), bf2f(hrb[(size_t)r.x * 32 + j]), a0);
        }
        float acc = (a0 + a1) + (a2 + a3);
        acc += __shfl_xor(acc, 32);
        if (half == 0) {
            float inv = 1.0f / fmaxf((float)dg, 1.0f);
            out[(size_t)n * 32 + j] = acc * inv + hro[(size_t)n * 32 + j];
        }
    }
}

extern "C" void kernel_launch(void* const* d_in, const int* in_sizes, int n_in,
                              void* d_out, int out_size, void* d_ws, size_t ws_size,
                              hipStream_t stream) {
    const float* x      = (const float*)d_in[0];
    const void*  ei_raw = d_in[1];
    const float* ea     = (const float*)d_in[2];
    const float* Wrel1  = (const float*)d_in[3];
    const float* brel1  = (const float*)d_in[4];
    const float* Wroot1 = (const float*)d_in[5];
    const float* Wrel2  = (const float*)d_in[6];
    const float* brel2  = (const float*)d_in[7];
    const float* Wroot2 = (const float*)d_in[8];
    float* out = (float*)d_out;

    const int N = in_sizes[0] / NF;          // 100000
    const int E = in_sizes[2];               // 1000000
    const int C  = (N + CMASK) >> CSHIFT;    // 782 coarse buckets
    const int B1 = (E + 4095) / 4096;        // 245 edge blocks
    const int M  = C * B1;                   // 191590
    const int nbM = (M + 1023) / 1024;       // 188

    // workspace layout
    long long* part = (long long*)d_ws;                 // E (8 MB)
    int2*  csr     = (int2*)(part + E);                 // E (8 MB); hb overlaps pre-p4
    int*   off     = (int*)(csr + E);                   // M
    int*   bsums   = off + M;                           // nbM (+pad)
    int*   flag    = bsums + 1024;                      // 1 (+3 pad)
    int*   deg     = flag + 4;                          // N
    int*   base    = deg + N;                           // N
    float* hro     = (float*)(base + N);                // N*32 fp32
    float* W1relT  = hro + (size_t)N * 32;              // 4096
    float* W1rootT = W1relT + 4096;                     // 4096
    float* W2T     = W1rootT + 4096;                    // 4096
    unsigned short* xb   = (unsigned short*)(W2T + 4096);  // N*64 bf16
    unsigned short* aggb = xb + (size_t)N * 64;            // N*64 bf16
    unsigned short* hrb  = aggb + (size_t)N * 64;          // N*32 bf16

    prep<<<2048, 256, 0, stream>>>((const unsigned*)ei_raw, flag, E,
                                   Wrel1, Wroot1, Wrel2, Wroot2,
                                   W1relT, W1rootT, W2T, x, xb, (long long)N * 16);
    p1_hist<<<B1, 1024, 0, stream>>>(ei_raw, flag, (int*)csr, E, C, B1);
    scan_k1<<<nbM, 1024, 0, stream>>>((int*)csr, off, bsums, M);
    scan_k2<<<1, 1024, 0, stream>>>(bsums, nbM);
    scan_k3<<<nbM, 1024, 0, stream>>>(off, bsums, M);
    p3_scatter<<<B1, 1024, 0, stream>>>(ei_raw, flag, ea, off, part, E, C, B1);
    p4_build<<<C, 256, 0, stream>>>(off, part, csr, deg, base, E, N, C, B1);

    gather1<<<2048, 256, 0, stream>>>(xb, csr, base, deg, aggb, N);
    node_fused<<<(N + 63) / 64, 256, 0, stream>>>(aggb, xb, W1relT, brel1, W1rootT,
                                                  W2T, brel2, hrb, hro, N);
    gather2<<<2048, 256, 0, stream>>>(hrb, hro, csr, base, deg, out, N);
}